// Round 1
// baseline (565.816 us; speedup 1.0000x reference)
//
#include <hip/hip_runtime.h>
#include <hip/hip_bf16.h>

#define NFFT 8192
#define TPB  512
#define VPT  16   // NFFT / TPB
#define ROWS 4    // rows per block: 2048/4 = 512 blocks = exactly 2 resident/CU

// Native 2-wide float vector => compiler emits v_pk_add_f32 / v_pk_fma_f32.
typedef float f2 __attribute__((ext_vector_type(2)));

__device__ __forceinline__ f2 mk(float a, float b){ f2 r; r.x=a; r.y=b; return r; }
__device__ __forceinline__ f2 cswap(f2 a){ return __builtin_shufflevector(a,a,1,0); }

// Raw barrier: lgkmcnt(0)+s_barrier in ONE opaque asm (memory clobber orders all
// LDS ops around it; single asm => nothing can be scheduled between wait and bar).
// Unlike __syncthreads() this does NOT drain vmcnt, so prefetch global_loads and
// output stores stay in flight across the whole FFT. All call sites are
// block-uniform control flow. LDS visibility needs only lgkmcnt(0)+s_barrier:
// no cross-wave communication goes through global memory in this kernel.
__device__ __forceinline__ void bar_lds() {
  asm volatile("s_waitcnt lgkmcnt(0)\n\ts_barrier" ::: "memory");
}

// XOR swizzle at f2 granularity (physical layout identical to R4/R5).
// Rounds below use closed-form identities so swz costs 0-2 VALU per access:
//   swz(p + 1024k) = swz(p) + 1024k
//   swz(b + 128k)  = (swz(b) ^ 8(k&1)) + 128k
//   swz(b + 16k)   = (b&~15) + 16k + ((b&15) ^ 8(blk&1) ^ k)
//   swz(16t + c)   = 16t + (c ^ (t&15))
__device__ __forceinline__ int swz(int j) { return j ^ ((j >> 4) & 15); }
__device__ __forceinline__ int rev13(unsigned x) { return (int)(__brev(x) >> 19); }

// d * (c - i s)  (forward twiddle)
__device__ __forceinline__ f2 cmul_conj(f2 d, float c, float s){
  return d*c + cswap(d)*mk(s,-s);
}
// v * (c + i s)  (inverse twiddle)
__device__ __forceinline__ f2 cmul_pos(f2 v, float c, float s){
  return v*c + cswap(v)*mk(-s,s);
}

// ---- radix-8 butterfly cores; hw sin/cos in revolutions (verified R2-R5) ----
__device__ __forceinline__ void dif8_core(f2* y, int p_num, float inv_den) {
  float cA[4], sA[4], cB[2], sB[2], c4, s4;
  {
    float r = (float)p_num * inv_den;
    float sa = __builtin_amdgcn_sinf(r);
    float ca = __builtin_amdgcn_cosf(r);
    float c2 = ca*ca - sa*sa, s2 = 2.0f*ca*sa;
    c4 = c2*c2 - s2*s2; s4 = 2.0f*c2*s2;
    const float R = 0.70710678118654752f;
    cA[0] = ca;          sA[0] = sa;
    cA[1] = R*(ca-sa);   sA[1] = R*(ca+sa);
    cA[2] = -sa;         sA[2] = ca;
    cA[3] = -R*(ca+sa);  sA[3] = R*(ca-sa);
    cB[0] = c2;  sB[0] = s2;
    cB[1] = -s2; sB[1] = c2;
  }
  #pragma unroll
  for (int k = 0; k < 4; ++k) {
    f2 u = y[k], v = y[k+4];
    y[k] = u + v;
    y[k+4] = cmul_conj(u - v, cA[k], sA[k]);
  }
  #pragma unroll
  for (int h = 0; h < 8; h += 4)
    #pragma unroll
    for (int k0 = 0; k0 < 2; ++k0) {
      f2 u = y[h+k0], v = y[h+k0+2];
      y[h+k0] = u + v;
      y[h+k0+2] = cmul_conj(u - v, cB[k0], sB[k0]);
    }
  #pragma unroll
  for (int h = 0; h < 8; h += 2) {
    f2 u = y[h], v = y[h+1];
    y[h] = u + v;
    y[h+1] = cmul_conj(u - v, c4, s4);
  }
}

__device__ __forceinline__ void dit8_core(f2* y, int p_num, float inv_den) {
  float cA[4], sA[4], cB[2], sB[2], c4, s4;
  {
    float r = (float)p_num * inv_den;
    float sa = __builtin_amdgcn_sinf(r);
    float ca = __builtin_amdgcn_cosf(r);
    float c2 = ca*ca - sa*sa, s2 = 2.0f*ca*sa;
    c4 = c2*c2 - s2*s2; s4 = 2.0f*c2*s2;
    const float R = 0.70710678118654752f;
    cA[0] = ca;          sA[0] = sa;
    cA[1] = R*(ca-sa);   sA[1] = R*(ca+sa);
    cA[2] = -sa;         sA[2] = ca;
    cA[3] = -R*(ca+sa);  sA[3] = R*(ca-sa);
    cB[0] = c2;  sB[0] = s2;
    cB[1] = -s2; sB[1] = c2;
  }
  #pragma unroll
  for (int h = 0; h < 8; h += 2) {
    f2 u = y[h];
    f2 w = cmul_pos(y[h+1], c4, s4);
    y[h] = u + w; y[h+1] = u - w;
  }
  #pragma unroll
  for (int h = 0; h < 8; h += 4)
    #pragma unroll
    for (int k0 = 0; k0 < 2; ++k0) {
      f2 u = y[h+k0];
      f2 w = cmul_pos(y[h+k0+2], cB[k0], sB[k0]);
      y[h+k0] = u + w; y[h+k0+2] = u - w;
    }
  #pragma unroll
  for (int k = 0; k < 4; ++k) {
    f2 u = y[k];
    f2 w = cmul_pos(y[k+4], cA[k], sA[k]);
    y[k] = u + w; y[k+4] = u - w;
  }
}

// ---- GLOBAL forward round S=1024: swz(p+1024k) = swz(p)+1024k -> imm offsets
__device__ __forceinline__ void dif_global1024(f2* z, int t) {
  #pragma unroll
  for (int gi = 0; gi < 2; ++gi) {
    int p = t + TPB*gi;
    f2* B = z + swz(p);
    f2 y[8];
    #pragma unroll
    for (int k = 0; k < 8; ++k) y[k] = B[1024*k];
    dif8_core(y, p, 0.125f/1024.0f);
    #pragma unroll
    for (int k = 0; k < 8; ++k) B[1024*k] = y[k];
  }
  bar_lds();
}

// ---- WAVE-LOCAL S=128: two bases (swz(b), swz(b)^8) + imm offsets.
// No fence: a wave's DS ops retire in order (lgkmcnt in-order for LDS),
// so own-wave read-after-write across rounds is safe and pipelines.
__device__ __forceinline__ void dif_wave128(f2* z, int w, int l) {
  #pragma unroll
  for (int gi = 0; gi < 2; ++gi) {
    int gl = l + 64*gi;
    int E = swz(w*1024 + gl);
    f2* B0 = z + E;
    f2* B1 = z + (E ^ 8);
    f2 y[8];
    #pragma unroll
    for (int k = 0; k < 8; ++k) y[k] = (k&1) ? B1[128*k] : B0[128*k];
    dif8_core(y, gl, 0.125f/128.0f);
    #pragma unroll
    for (int k = 0; k < 8; ++k) { if (k&1) B1[128*k] = y[k]; else B0[128*k] = y[k]; }
  }
}

__device__ __forceinline__ void dit_wave128(f2* z, int w, int l) {
  #pragma unroll
  for (int gi = 0; gi < 2; ++gi) {
    int gl = l + 64*gi;
    int E = swz(w*1024 + gl);
    f2* B0 = z + E;
    f2* B1 = z + (E ^ 8);
    f2 y[8];
    #pragma unroll
    for (int k = 0; k < 8; ++k) y[k] = (k&1) ? B1[128*k] : B0[128*k];
    dit8_core(y, gl, 0.125f/128.0f);
    #pragma unroll
    for (int k = 0; k < 8; ++k) { if (k&1) B1[128*k] = y[k]; else B0[128*k] = y[k]; }
  }
}

// ---- WAVE-LOCAL S=16: swz(b+16k) = H + 16k + (e^k), e = p ^ 8(blk&1)
__device__ __forceinline__ void dif_wave16(f2* z, int w, int l) {
  #pragma unroll
  for (int gi = 0; gi < 2; ++gi) {
    int gl = l + 64*gi;
    int p = gl & 15, blk = gl >> 4;
    int e = p ^ (8*(blk&1));
    f2* H = z + (w*1024 + blk*128);
    f2 y[8];
    #pragma unroll
    for (int k = 0; k < 8; ++k) y[k] = H[16*k + (e ^ k)];
    dif8_core(y, p, 0.125f/16.0f);
    #pragma unroll
    for (int k = 0; k < 8; ++k) H[16*k + (e ^ k)] = y[k];
  }
}

__device__ __forceinline__ void dit_wave16(f2* z, int w, int l) {
  #pragma unroll
  for (int gi = 0; gi < 2; ++gi) {
    int gl = l + 64*gi;
    int p = gl & 15, blk = gl >> 4;
    int e = p ^ (8*(blk&1));
    f2* H = z + (w*1024 + blk*128);
    f2 y[8];
    #pragma unroll
    for (int k = 0; k < 8; ++k) y[k] = H[16*k + (e ^ k)];
    dit8_core(y, p, 0.125f/16.0f);
    #pragma unroll
    for (int k = 0; k < 8; ++k) H[16*k + (e ^ k)] = y[k];
  }
}

#define C16_1 0.92387953251128674f
#define S16_1 0.38268343236508978f
#define RSQ2  0.70710678118654752f

// ---- radix-16 const-twiddle rounds: swz(16t+c) = 16t + (c ^ (t&15))
__device__ __forceinline__ void dif16_x(f2* z, int t) {
  const float C8[8] = {1.f, C16_1, RSQ2, S16_1, 0.f, -S16_1, -RSQ2, -C16_1};
  const float S8[8] = {0.f, S16_1, RSQ2, C16_1, 1.f,  C16_1,  RSQ2,  S16_1};
  int e = t & 15;
  f2* H = z + 16*t;
  f2 y[16];
  #pragma unroll
  for (int c = 0; c < 16; ++c) y[c] = H[c ^ e];
  #pragma unroll
  for (int j = 0; j < 8; ++j) {
    f2 u = y[j], v = y[j+8];
    y[j] = u + v;
    y[j+8] = cmul_conj(u - v, C8[j], S8[j]);
  }
  #pragma unroll
  for (int h = 0; h < 16; h += 8)
    #pragma unroll
    for (int j = 0; j < 4; ++j) {
      f2 u = y[h+j], v = y[h+j+4];
      y[h+j] = u + v;
      y[h+j+4] = cmul_conj(u - v, C8[2*j], S8[2*j]);
    }
  #pragma unroll
  for (int h = 0; h < 16; h += 4)
    #pragma unroll
    for (int j = 0; j < 2; ++j) {
      f2 u = y[h+j], v = y[h+j+2];
      y[h+j] = u + v;
      f2 d = u - v;
      y[h+j+2] = j ? mk(d.y, -d.x) : d;
    }
  #pragma unroll
  for (int h = 0; h < 16; h += 2) {
    f2 u = y[h], v = y[h+1];
    y[h] = u + v; y[h+1] = u - v;
  }
  #pragma unroll
  for (int c = 0; c < 16; ++c) H[c ^ e] = y[c];
}

__device__ __forceinline__ void dit16_x(f2* z, int t) {
  const float C8[8] = {1.f, C16_1, RSQ2, S16_1, 0.f, -S16_1, -RSQ2, -C16_1};
  const float S8[8] = {0.f, S16_1, RSQ2, C16_1, 1.f,  C16_1,  RSQ2,  S16_1};
  int e = t & 15;
  f2* H = z + 16*t;
  f2 y[16];
  #pragma unroll
  for (int c = 0; c < 16; ++c) y[c] = H[c ^ e];
  #pragma unroll
  for (int h = 0; h < 16; h += 2) {
    f2 u = y[h], v = y[h+1];
    y[h] = u + v; y[h+1] = u - v;
  }
  #pragma unroll
  for (int h = 0; h < 16; h += 4)
    #pragma unroll
    for (int j = 0; j < 2; ++j) {
      f2 u = y[h+j];
      f2 v = y[h+j+2];
      f2 w = j ? mk(-v.y, v.x) : v;
      y[h+j] = u + w; y[h+j+2] = u - w;
    }
  #pragma unroll
  for (int h = 0; h < 16; h += 8)
    #pragma unroll
    for (int j = 0; j < 4; ++j) {
      f2 u = y[h+j];
      f2 w = cmul_pos(y[h+j+4], C8[2*j], S8[2*j]);
      y[h+j] = u + w; y[h+j+4] = u - w;
    }
  #pragma unroll
  for (int j = 0; j < 8; ++j) {
    f2 u = y[j];
    f2 w = cmul_pos(y[j+8], C8[j], S8[j]);
    y[j] = u + w; y[j+8] = u - w;
  }
  #pragma unroll
  for (int c = 0; c < 16; ++c) H[c ^ e] = y[c];
}

// Last inverse round (global S=1024): imm offsets; results stay in registers.
__device__ __forceinline__ void dit_last(const f2* z, int t, float* re, float& mv) {
  #pragma unroll
  for (int gi = 0; gi < 2; ++gi) {
    int g = t + TPB*gi;
    const f2* B = z + swz(g);
    f2 y[8];
    #pragma unroll
    for (int k = 0; k < 8; ++k) y[k] = B[1024*k];
    dit8_core(y, g, 0.125f/1024.0f);
    #pragma unroll
    for (int k = 0; k < 8; ++k) {
      re[8*gi + k] = y[k].x;     // corr*N at position g + 1024*k
      mv = fmaxf(mv, y[k].x);
    }
  }
}

// __launch_bounds__(512,4): cap VGPR at 128 (LDS already caps at 16 waves/CU =
// 4/SIMD, so up to 128 VGPRs are free; est. use ~112 incl. 32 prefetch regs).
__global__ __launch_bounds__(TPB, 4)
void corr_align_kernel(const float* __restrict__ x, const float* __restrict__ xref,
                       float* __restrict__ out0, float* __restrict__ outInd,
                       int nrows) {
  __shared__ f2 z[NFFT];   // 64 KiB
  const int t = threadIdx.x;
  const int lane = t & 63, wave = t >> 6;
  const int row0 = blockIdx.x * ROWS;
  const int rmax = (nrows - row0 < ROWS) ? (nrows - row0) : ROWS;

  // ---- prefetch row0 inputs into registers (8x dwordx4 = 32 VGPRs) ----
  float4 sx[4], sr[4];
  {
    const float4* x4 = (const float4*)(x + (size_t)row0 * NFFT);
    const float4* r4 = (const float4*)(xref + (size_t)row0 * NFFT);
    #pragma unroll
    for (int gi = 0; gi < 4; ++gi) { int q = t + TPB*gi; sx[gi] = x4[q]; sr[gi] = r4[q]; }
  }

  for (int r = 0; r < rmax; ++r) {
    const int row = row0 + r;
    const float* xrow = x + (size_t)row * NFFT;
    const float* rrow = xref + (size_t)row * NFFT;

    // z was argmax scratch for the previous row: all readers must be done.
    bar_lds();

    // ---- stage: z[n] = x[n] + i*xref[n] (from prefetched regs) ----
    #pragma unroll
    for (int gi = 0; gi < 4; ++gi) {
      int q = t + TPB*gi;
      float4 xv = sx[gi], rv = sr[gi];
      int j = 4*q;
      z[swz(j+0)] = mk(xv.x, rv.x);
      z[swz(j+1)] = mk(xv.y, rv.y);
      z[swz(j+2)] = mk(xv.z, rv.z);
      z[swz(j+3)] = mk(xv.w, rv.w);
    }
    bar_lds();   // lgkmcnt(0) also makes the sx/sr overwrite below WAR-safe

    // ---- prefetch next row NOW; bar_lds never drains vmcnt, so these loads
    //      stay in flight under the entire FFT below. ----
    if (r + 1 < rmax) {
      const float4* x4 = (const float4*)(x + (size_t)(row + 1) * NFFT);
      const float4* r4 = (const float4*)(xref + (size_t)(row + 1) * NFFT);
      #pragma unroll
      for (int gi = 0; gi < 4; ++gi) { int q = t + TPB*gi; sx[gi] = x4[q]; sr[gi] = r4[q]; }
    }

    // ---- forward DIF FFT: natural -> bit-reversed ----
    dif_global1024(z, t);          // cross-wave, bar_lds inside
    dif_wave128(z, wave, lane);    // wave-local: own-chunk, DS-order safe
    dif_wave16(z, wave, lane);
    dif16_x(z, t);
    bar_lds();                     // unpack reads cross-chunk

    // ---- unpack + cross-spectrum, PAIR-OWNED ----
    #pragma unroll
    for (int gi = 0; gi < 8; ++gi) {
      int k = 8*t + gi + 1;                       // 1..4096
      int p = rev13((unsigned)k);
      int q = rev13((unsigned)((NFFT - k) & (NFFT-1)));
      f2 Zp = z[swz(p)];
      f2 Zq = z[swz(q)];
      float Xx = 0.5f*(Zp.x + Zq.x);
      float Xy = 0.5f*(Zp.y - Zq.y);
      float Yx = 0.5f*(Zp.y + Zq.y);
      float Yy = 0.5f*(Zq.x - Zp.x);
      f2 Gk = mk(Xx*Yx + Xy*Yy, Xx*Yy - Xy*Yx);
      z[swz(p)] = Gk;
      if (k != NFFT/2) z[swz(q)] = mk(Gk.x, -Gk.y);
    }
    if (t == 0) {
      f2 Z0 = z[0];
      z[0] = mk(Z0.x * Z0.y, 0.0f);
    }
    bar_lds();

    // ---- inverse DIT FFT: bit-reversed -> natural ----
    dit16_x(z, t);
    dit_wave16(z, wave, lane);
    dit_wave128(z, wave, lane);
    bar_lds();                     // last round reads cross-chunk
    float re[16];
    float mv = -3.0e38f;
    dit_last(z, t, re, mv);        // corr values stay in registers
    bar_lds();                     // z becomes argmax scratch

    // ---- argmax: wave max -> block max -> candidate scan in registers ----
    float* zf = (float*)z;
    int*  zi = (int*)z;
    if (t == 0) zi[8] = 0;
    #pragma unroll
    for (int off = 32; off > 0; off >>= 1)
      mv = fmaxf(mv, __shfl_down(mv, off));
    if (lane == 0) zf[wave] = mv;
    bar_lds();
    float M = zf[0];
    #pragma unroll
    for (int w = 1; w < 8; ++w) M = fmaxf(M, zf[w]);
    // margin 4.0 corr units = 32768 raw (>>100x f32 FFT error bound).
    float thresh = M - 32768.0f;
    #pragma unroll
    for (int gi = 0; gi < 2; ++gi)
      #pragma unroll
      for (int k = 0; k < 8; ++k) {
        if (re[8*gi + k] >= thresh) {
          int pos = t + TPB*gi + 1024*k;
          int slot = atomicAdd(&zi[8], 1);
          if (slot < 40) zi[16 + slot] = pos;
        }
      }
    bar_lds();
    int count = zi[8];
    if (count > 40) count = 40;

    int bestPos;
    if (count == 1) {
      bestPos = zi[16];
    } else {
      // fp64 exact dot per candidate (np reference FFT is float64)
      double* zd = (double*)z;
      double bestV = -1.0e300;
      int bp = NFFT;
      for (int c = 0; c < count; ++c) {
        int pos = zi[16 + c];
        double part = 0.0;
        #pragma unroll 4
        for (int gi = 0; gi < VPT; ++gi) {
          int n = t + TPB*gi;
          part += (double)xrow[n] * (double)rrow[(n + pos) & (NFFT-1)];
        }
        #pragma unroll
        for (int off = 32; off > 0; off >>= 1)
          part += __shfl_down(part, off);
        if (lane == 0) zd[32 + wave] = part;
        bar_lds();
        if (t == 0) {
          double tot = 0.0;
          #pragma unroll
          for (int w = 0; w < 8; ++w) tot += zd[32 + w];
          if (tot > bestV || (tot == bestV && pos < bp)) { bestV = tot; bp = pos; }
        }
        bar_lds();
      }
      if (t == 0) zi[9] = bp;
      bar_lds();
      bestPos = zi[9];
    }

    // ---- outputs: x_aligned[k] = x[(k - ind) mod N]; inds as float.
    //      Stores are fire-and-forget: next row's bar_lds never drains vmcnt.
    float* orow = out0 + (size_t)row * NFFT;
    #pragma unroll 4
    for (int gi = 0; gi < VPT; ++gi) {
      int kk = t + TPB*gi;
      orow[kk] = xrow[(kk - bestPos) & (NFFT-1)];
    }
    if (t == 0) outInd[row] = (float)bestPos;
  }
}

extern "C" void kernel_launch(void* const* d_in, const int* in_sizes, int n_in,
                              void* d_out, int out_size, void* d_ws, size_t ws_size,
                              hipStream_t stream) {
  const float* x    = (const float*)d_in[0];
  const float* xref = (const float*)d_in[1];
  float* out = (float*)d_out;
  const int rows = in_sizes[0] / NFFT;   // 32*64 = 2048
  float* outInd = out + (size_t)rows * NFFT;
  const int grid = (rows + ROWS - 1) / ROWS;   // 512 blocks = 2/CU resident
  hipLaunchKernelGGL(corr_align_kernel, dim3(grid), dim3(TPB), 0, stream,
                     x, xref, out, outInd, rows);
}

// Round 2
// 416.416 us; speedup vs baseline: 1.3588x; 1.3588x over previous
//
#include <hip/hip_runtime.h>
#include <hip/hip_bf16.h>

#define NFFT 8192
#define TPB  512
#define VPT  16   // NFFT / TPB
#define ROWS 4    // rows per block: 2048/4 = 512 blocks = exactly 2 resident/CU

// Native 2-wide float vector => compiler emits v_pk_add_f32 / v_pk_fma_f32.
typedef float f2 __attribute__((ext_vector_type(2)));

__device__ __forceinline__ f2 mk(float a, float b){ f2 r; r.x=a; r.y=b; return r; }
__device__ __forceinline__ f2 cswap(f2 a){ return __builtin_shufflevector(a,a,1,0); }

// Raw barrier: lgkmcnt(0)+s_barrier in ONE opaque asm (memory clobber orders all
// LDS ops around it; single asm => nothing can be scheduled between wait and bar).
// Unlike __syncthreads() this does NOT drain vmcnt, so prefetch global_loads and
// output stores stay in flight across the whole FFT. All call sites are
// block-uniform control flow. LDS visibility needs only lgkmcnt(0)+s_barrier:
// no cross-wave communication goes through global memory in this kernel.
__device__ __forceinline__ void bar_lds() {
  asm volatile("s_waitcnt lgkmcnt(0)\n\ts_barrier" ::: "memory");
}

// XOR swizzle at f2 granularity (physical layout identical to R4/R5).
// Rounds below use closed-form identities so swz costs 0-2 VALU per access:
//   swz(p + 1024k) = swz(p) + 1024k
//   swz(b + 128k)  = (swz(b) ^ 8(k&1)) + 128k
//   swz(b + 16k)   = (b&~15) + 16k + ((b&15) ^ 8(blk&1) ^ k)
//   swz(16t + c)   = 16t + (c ^ (t&15))
__device__ __forceinline__ int swz(int j) { return j ^ ((j >> 4) & 15); }
__device__ __forceinline__ int rev13(unsigned x) { return (int)(__brev(x) >> 19); }

// d * (c - i s)  (forward twiddle)
__device__ __forceinline__ f2 cmul_conj(f2 d, float c, float s){
  return d*c + cswap(d)*mk(s,-s);
}
// v * (c + i s)  (inverse twiddle)
__device__ __forceinline__ f2 cmul_pos(f2 v, float c, float s){
  return v*c + cswap(v)*mk(-s,s);
}

// ---- radix-8 butterfly cores; hw sin/cos in revolutions (verified R2-R5) ----
__device__ __forceinline__ void dif8_core(f2* y, int p_num, float inv_den) {
  float cA[4], sA[4], cB[2], sB[2], c4, s4;
  {
    float r = (float)p_num * inv_den;
    float sa = __builtin_amdgcn_sinf(r);
    float ca = __builtin_amdgcn_cosf(r);
    float c2 = ca*ca - sa*sa, s2 = 2.0f*ca*sa;
    c4 = c2*c2 - s2*s2; s4 = 2.0f*c2*s2;
    const float R = 0.70710678118654752f;
    cA[0] = ca;          sA[0] = sa;
    cA[1] = R*(ca-sa);   sA[1] = R*(ca+sa);
    cA[2] = -sa;         sA[2] = ca;
    cA[3] = -R*(ca+sa);  sA[3] = R*(ca-sa);
    cB[0] = c2;  sB[0] = s2;
    cB[1] = -s2; sB[1] = c2;
  }
  #pragma unroll
  for (int k = 0; k < 4; ++k) {
    f2 u = y[k], v = y[k+4];
    y[k] = u + v;
    y[k+4] = cmul_conj(u - v, cA[k], sA[k]);
  }
  #pragma unroll
  for (int h = 0; h < 8; h += 4)
    #pragma unroll
    for (int k0 = 0; k0 < 2; ++k0) {
      f2 u = y[h+k0], v = y[h+k0+2];
      y[h+k0] = u + v;
      y[h+k0+2] = cmul_conj(u - v, cB[k0], sB[k0]);
    }
  #pragma unroll
  for (int h = 0; h < 8; h += 2) {
    f2 u = y[h], v = y[h+1];
    y[h] = u + v;
    y[h+1] = cmul_conj(u - v, c4, s4);
  }
}

__device__ __forceinline__ void dit8_core(f2* y, int p_num, float inv_den) {
  float cA[4], sA[4], cB[2], sB[2], c4, s4;
  {
    float r = (float)p_num * inv_den;
    float sa = __builtin_amdgcn_sinf(r);
    float ca = __builtin_amdgcn_cosf(r);
    float c2 = ca*ca - sa*sa, s2 = 2.0f*ca*sa;
    c4 = c2*c2 - s2*s2; s4 = 2.0f*c2*s2;
    const float R = 0.70710678118654752f;
    cA[0] = ca;          sA[0] = sa;
    cA[1] = R*(ca-sa);   sA[1] = R*(ca+sa);
    cA[2] = -sa;         sA[2] = ca;
    cA[3] = -R*(ca+sa);  sA[3] = R*(ca-sa);
    cB[0] = c2;  sB[0] = s2;
    cB[1] = -s2; sB[1] = c2;
  }
  #pragma unroll
  for (int h = 0; h < 8; h += 2) {
    f2 u = y[h];
    f2 w = cmul_pos(y[h+1], c4, s4);
    y[h] = u + w; y[h+1] = u - w;
  }
  #pragma unroll
  for (int h = 0; h < 8; h += 4)
    #pragma unroll
    for (int k0 = 0; k0 < 2; ++k0) {
      f2 u = y[h+k0];
      f2 w = cmul_pos(y[h+k0+2], cB[k0], sB[k0]);
      y[h+k0] = u + w; y[h+k0+2] = u - w;
    }
  #pragma unroll
  for (int k = 0; k < 4; ++k) {
    f2 u = y[k];
    f2 w = cmul_pos(y[k+4], cA[k], sA[k]);
    y[k] = u + w; y[k+4] = u - w;
  }
}

// ---- GLOBAL forward round S=1024: swz(p+1024k) = swz(p)+1024k -> imm offsets
__device__ __forceinline__ void dif_global1024(f2* z, int t) {
  #pragma unroll
  for (int gi = 0; gi < 2; ++gi) {
    int p = t + TPB*gi;
    f2* B = z + swz(p);
    f2 y[8];
    #pragma unroll
    for (int k = 0; k < 8; ++k) y[k] = B[1024*k];
    dif8_core(y, p, 0.125f/1024.0f);
    #pragma unroll
    for (int k = 0; k < 8; ++k) B[1024*k] = y[k];
  }
  bar_lds();
}

// ---- WAVE-LOCAL S=128: two bases (swz(b), swz(b)^8) + imm offsets.
// No fence: a wave's DS ops retire in order (lgkmcnt in-order for LDS),
// so own-wave read-after-write across rounds is safe and pipelines.
__device__ __forceinline__ void dif_wave128(f2* z, int w, int l) {
  #pragma unroll
  for (int gi = 0; gi < 2; ++gi) {
    int gl = l + 64*gi;
    int E = swz(w*1024 + gl);
    f2* B0 = z + E;
    f2* B1 = z + (E ^ 8);
    f2 y[8];
    #pragma unroll
    for (int k = 0; k < 8; ++k) y[k] = (k&1) ? B1[128*k] : B0[128*k];
    dif8_core(y, gl, 0.125f/128.0f);
    #pragma unroll
    for (int k = 0; k < 8; ++k) { if (k&1) B1[128*k] = y[k]; else B0[128*k] = y[k]; }
  }
}

__device__ __forceinline__ void dit_wave128(f2* z, int w, int l) {
  #pragma unroll
  for (int gi = 0; gi < 2; ++gi) {
    int gl = l + 64*gi;
    int E = swz(w*1024 + gl);
    f2* B0 = z + E;
    f2* B1 = z + (E ^ 8);
    f2 y[8];
    #pragma unroll
    for (int k = 0; k < 8; ++k) y[k] = (k&1) ? B1[128*k] : B0[128*k];
    dit8_core(y, gl, 0.125f/128.0f);
    #pragma unroll
    for (int k = 0; k < 8; ++k) { if (k&1) B1[128*k] = y[k]; else B0[128*k] = y[k]; }
  }
}

// ---- WAVE-LOCAL S=16: swz(b+16k) = H + 16k + (e^k), e = p ^ 8(blk&1)
__device__ __forceinline__ void dif_wave16(f2* z, int w, int l) {
  #pragma unroll
  for (int gi = 0; gi < 2; ++gi) {
    int gl = l + 64*gi;
    int p = gl & 15, blk = gl >> 4;
    int e = p ^ (8*(blk&1));
    f2* H = z + (w*1024 + blk*128);
    f2 y[8];
    #pragma unroll
    for (int k = 0; k < 8; ++k) y[k] = H[16*k + (e ^ k)];
    dif8_core(y, p, 0.125f/16.0f);
    #pragma unroll
    for (int k = 0; k < 8; ++k) H[16*k + (e ^ k)] = y[k];
  }
}

__device__ __forceinline__ void dit_wave16(f2* z, int w, int l) {
  #pragma unroll
  for (int gi = 0; gi < 2; ++gi) {
    int gl = l + 64*gi;
    int p = gl & 15, blk = gl >> 4;
    int e = p ^ (8*(blk&1));
    f2* H = z + (w*1024 + blk*128);
    f2 y[8];
    #pragma unroll
    for (int k = 0; k < 8; ++k) y[k] = H[16*k + (e ^ k)];
    dit8_core(y, p, 0.125f/16.0f);
    #pragma unroll
    for (int k = 0; k < 8; ++k) H[16*k + (e ^ k)] = y[k];
  }
}

#define C16_1 0.92387953251128674f
#define S16_1 0.38268343236508978f
#define RSQ2  0.70710678118654752f

// ---- radix-16 const-twiddle rounds: swz(16t+c) = 16t + (c ^ (t&15))
__device__ __forceinline__ void dif16_x(f2* z, int t) {
  const float C8[8] = {1.f, C16_1, RSQ2, S16_1, 0.f, -S16_1, -RSQ2, -C16_1};
  const float S8[8] = {0.f, S16_1, RSQ2, C16_1, 1.f,  C16_1,  RSQ2,  S16_1};
  int e = t & 15;
  f2* H = z + 16*t;
  f2 y[16];
  #pragma unroll
  for (int c = 0; c < 16; ++c) y[c] = H[c ^ e];
  #pragma unroll
  for (int j = 0; j < 8; ++j) {
    f2 u = y[j], v = y[j+8];
    y[j] = u + v;
    y[j+8] = cmul_conj(u - v, C8[j], S8[j]);
  }
  #pragma unroll
  for (int h = 0; h < 16; h += 8)
    #pragma unroll
    for (int j = 0; j < 4; ++j) {
      f2 u = y[h+j], v = y[h+j+4];
      y[h+j] = u + v;
      y[h+j+4] = cmul_conj(u - v, C8[2*j], S8[2*j]);
    }
  #pragma unroll
  for (int h = 0; h < 16; h += 4)
    #pragma unroll
    for (int j = 0; j < 2; ++j) {
      f2 u = y[h+j], v = y[h+j+2];
      y[h+j] = u + v;
      f2 d = u - v;
      y[h+j+2] = j ? mk(d.y, -d.x) : d;
    }
  #pragma unroll
  for (int h = 0; h < 16; h += 2) {
    f2 u = y[h], v = y[h+1];
    y[h] = u + v; y[h+1] = u - v;
  }
  #pragma unroll
  for (int c = 0; c < 16; ++c) H[c ^ e] = y[c];
}

__device__ __forceinline__ void dit16_x(f2* z, int t) {
  const float C8[8] = {1.f, C16_1, RSQ2, S16_1, 0.f, -S16_1, -RSQ2, -C16_1};
  const float S8[8] = {0.f, S16_1, RSQ2, C16_1, 1.f,  C16_1,  RSQ2,  S16_1};
  int e = t & 15;
  f2* H = z + 16*t;
  f2 y[16];
  #pragma unroll
  for (int c = 0; c < 16; ++c) y[c] = H[c ^ e];
  #pragma unroll
  for (int h = 0; h < 16; h += 2) {
    f2 u = y[h], v = y[h+1];
    y[h] = u + v; y[h+1] = u - v;
  }
  #pragma unroll
  for (int h = 0; h < 16; h += 4)
    #pragma unroll
    for (int j = 0; j < 2; ++j) {
      f2 u = y[h+j];
      f2 v = y[h+j+2];
      f2 w = j ? mk(-v.y, v.x) : v;
      y[h+j] = u + w; y[h+j+2] = u - w;
    }
  #pragma unroll
  for (int h = 0; h < 16; h += 8)
    #pragma unroll
    for (int j = 0; j < 4; ++j) {
      f2 u = y[h+j];
      f2 w = cmul_pos(y[h+j+4], C8[2*j], S8[2*j]);
      y[h+j] = u + w; y[h+j+4] = u - w;
    }
  #pragma unroll
  for (int j = 0; j < 8; ++j) {
    f2 u = y[j];
    f2 w = cmul_pos(y[j+8], C8[j], S8[j]);
    y[j] = u + w; y[j+8] = u - w;
  }
  #pragma unroll
  for (int c = 0; c < 16; ++c) H[c ^ e] = y[c];
}

// Last inverse round (global S=1024): imm offsets; results stay in registers.
__device__ __forceinline__ void dit_last(const f2* z, int t, float* re, float& mv) {
  #pragma unroll
  for (int gi = 0; gi < 2; ++gi) {
    int g = t + TPB*gi;
    const f2* B = z + swz(g);
    f2 y[8];
    #pragma unroll
    for (int k = 0; k < 8; ++k) y[k] = B[1024*k];
    dit8_core(y, g, 0.125f/1024.0f);
    #pragma unroll
    for (int k = 0; k < 8; ++k) {
      re[8*gi + k] = y[k].x;     // corr*N at position g + 1024*k
      mv = fmaxf(mv, y[k].x);
    }
  }
}

// NO waves-per-EU constraint: R2 and Round-1 both showed a min-occupancy bound
// makes the compiler target 64 VGPR and spill ~1.1 GB to scratch (470 us).
// Plain max-threads bound gave VGPR=80 spill-free; +32 prefetch regs ~= 112,
// still within the 128-VGPR / 16-wave (LDS-capped 2 blocks/CU) envelope.
__global__ __launch_bounds__(TPB)
void corr_align_kernel(const float* __restrict__ x, const float* __restrict__ xref,
                       float* __restrict__ out0, float* __restrict__ outInd,
                       int nrows) {
  __shared__ f2 z[NFFT];   // 64 KiB
  const int t = threadIdx.x;
  const int lane = t & 63, wave = t >> 6;
  const int row0 = blockIdx.x * ROWS;
  const int rmax = (nrows - row0 < ROWS) ? (nrows - row0) : ROWS;

  // ---- prefetch row0 inputs into registers (8x dwordx4 = 32 VGPRs) ----
  float4 sx[4], sr[4];
  {
    const float4* x4 = (const float4*)(x + (size_t)row0 * NFFT);
    const float4* r4 = (const float4*)(xref + (size_t)row0 * NFFT);
    #pragma unroll
    for (int gi = 0; gi < 4; ++gi) { int q = t + TPB*gi; sx[gi] = x4[q]; sr[gi] = r4[q]; }
  }

  for (int r = 0; r < rmax; ++r) {
    const int row = row0 + r;
    const float* xrow = x + (size_t)row * NFFT;
    const float* rrow = xref + (size_t)row * NFFT;

    // z was argmax scratch for the previous row: all readers must be done.
    bar_lds();

    // ---- stage: z[n] = x[n] + i*xref[n] (from prefetched regs) ----
    #pragma unroll
    for (int gi = 0; gi < 4; ++gi) {
      int q = t + TPB*gi;
      float4 xv = sx[gi], rv = sr[gi];
      int j = 4*q;
      z[swz(j+0)] = mk(xv.x, rv.x);
      z[swz(j+1)] = mk(xv.y, rv.y);
      z[swz(j+2)] = mk(xv.z, rv.z);
      z[swz(j+3)] = mk(xv.w, rv.w);
    }
    bar_lds();   // lgkmcnt(0) also makes the sx/sr overwrite below WAR-safe

    // ---- prefetch next row NOW; bar_lds never drains vmcnt, so these loads
    //      stay in flight under the entire FFT below. ----
    if (r + 1 < rmax) {
      const float4* x4 = (const float4*)(x + (size_t)(row + 1) * NFFT);
      const float4* r4 = (const float4*)(xref + (size_t)(row + 1) * NFFT);
      #pragma unroll
      for (int gi = 0; gi < 4; ++gi) { int q = t + TPB*gi; sx[gi] = x4[q]; sr[gi] = r4[q]; }
    }

    // ---- forward DIF FFT: natural -> bit-reversed ----
    dif_global1024(z, t);          // cross-wave, bar_lds inside
    dif_wave128(z, wave, lane);    // wave-local: own-chunk, DS-order safe
    dif_wave16(z, wave, lane);
    dif16_x(z, t);
    bar_lds();                     // unpack reads cross-chunk

    // ---- unpack + cross-spectrum, PAIR-OWNED ----
    #pragma unroll
    for (int gi = 0; gi < 8; ++gi) {
      int k = 8*t + gi + 1;                       // 1..4096
      int p = rev13((unsigned)k);
      int q = rev13((unsigned)((NFFT - k) & (NFFT-1)));
      f2 Zp = z[swz(p)];
      f2 Zq = z[swz(q)];
      float Xx = 0.5f*(Zp.x + Zq.x);
      float Xy = 0.5f*(Zp.y - Zq.y);
      float Yx = 0.5f*(Zp.y + Zq.y);
      float Yy = 0.5f*(Zq.x - Zp.x);
      f2 Gk = mk(Xx*Yx + Xy*Yy, Xx*Yy - Xy*Yx);
      z[swz(p)] = Gk;
      if (k != NFFT/2) z[swz(q)] = mk(Gk.x, -Gk.y);
    }
    if (t == 0) {
      f2 Z0 = z[0];
      z[0] = mk(Z0.x * Z0.y, 0.0f);
    }
    bar_lds();

    // ---- inverse DIT FFT: bit-reversed -> natural ----
    dit16_x(z, t);
    dit_wave16(z, wave, lane);
    dit_wave128(z, wave, lane);
    bar_lds();                     // last round reads cross-chunk
    float re[16];
    float mv = -3.0e38f;
    dit_last(z, t, re, mv);        // corr values stay in registers
    bar_lds();                     // z becomes argmax scratch

    // ---- argmax: wave max -> block max -> candidate scan in registers ----
    float* zf = (float*)z;
    int*  zi = (int*)z;
    if (t == 0) zi[8] = 0;
    #pragma unroll
    for (int off = 32; off > 0; off >>= 1)
      mv = fmaxf(mv, __shfl_down(mv, off));
    if (lane == 0) zf[wave] = mv;
    bar_lds();
    float M = zf[0];
    #pragma unroll
    for (int w = 1; w < 8; ++w) M = fmaxf(M, zf[w]);
    // margin 4.0 corr units = 32768 raw (>>100x f32 FFT error bound).
    float thresh = M - 32768.0f;
    #pragma unroll
    for (int gi = 0; gi < 2; ++gi)
      #pragma unroll
      for (int k = 0; k < 8; ++k) {
        if (re[8*gi + k] >= thresh) {
          int pos = t + TPB*gi + 1024*k;
          int slot = atomicAdd(&zi[8], 1);
          if (slot < 40) zi[16 + slot] = pos;
        }
      }
    bar_lds();
    int count = zi[8];
    if (count > 40) count = 40;

    int bestPos;
    if (count == 1) {
      bestPos = zi[16];
    } else {
      // fp64 exact dot per candidate (np reference FFT is float64)
      double* zd = (double*)z;
      double bestV = -1.0e300;
      int bp = NFFT;
      for (int c = 0; c < count; ++c) {
        int pos = zi[16 + c];
        double part = 0.0;
        #pragma unroll 4
        for (int gi = 0; gi < VPT; ++gi) {
          int n = t + TPB*gi;
          part += (double)xrow[n] * (double)rrow[(n + pos) & (NFFT-1)];
        }
        #pragma unroll
        for (int off = 32; off > 0; off >>= 1)
          part += __shfl_down(part, off);
        if (lane == 0) zd[32 + wave] = part;
        bar_lds();
        if (t == 0) {
          double tot = 0.0;
          #pragma unroll
          for (int w = 0; w < 8; ++w) tot += zd[32 + w];
          if (tot > bestV || (tot == bestV && pos < bp)) { bestV = tot; bp = pos; }
        }
        bar_lds();
      }
      if (t == 0) zi[9] = bp;
      bar_lds();
      bestPos = zi[9];
    }

    // ---- outputs: x_aligned[k] = x[(k - ind) mod N]; inds as float.
    //      Stores are fire-and-forget: next row's bar_lds never drains vmcnt.
    float* orow = out0 + (size_t)row * NFFT;
    #pragma unroll 4
    for (int gi = 0; gi < VPT; ++gi) {
      int kk = t + TPB*gi;
      orow[kk] = xrow[(kk - bestPos) & (NFFT-1)];
    }
    if (t == 0) outInd[row] = (float)bestPos;
  }
}

extern "C" void kernel_launch(void* const* d_in, const int* in_sizes, int n_in,
                              void* d_out, int out_size, void* d_ws, size_t ws_size,
                              hipStream_t stream) {
  const float* x    = (const float*)d_in[0];
  const float* xref = (const float*)d_in[1];
  float* out = (float*)d_out;
  const int rows = in_sizes[0] / NFFT;   // 32*64 = 2048
  float* outInd = out + (size_t)rows * NFFT;
  const int grid = (rows + ROWS - 1) / ROWS;   // 512 blocks = 2/CU resident
  hipLaunchKernelGGL(corr_align_kernel, dim3(grid), dim3(TPB), 0, stream,
                     x, xref, out, outInd, rows);
}